// Round 5
// baseline (1418.541 us; speedup 1.0000x reference)
//
#include <hip/hip_runtime.h>
#include <hip/hip_bf16.h>
#include <stdint.h>

// DeepFakeDetectionModel: stem LN(26)->Linear(26->1024)->ReLU, 8x [LN->Linear(1024->1024)->ReLU],
// head LN->Linear(1024->1)->sigmoid.  B=65536.
//
// LN folded into weights (W'=gamma*W fp16, S'=sum W', b'=b+beta@W^T); GEMMs run on RAW fp16
// activations; LN affine applied in epilogue from per-row (sum,sumsq) stats.
// R2: 256x256 tile, T2 swizzle (bank conflicts 2.5e7 -> 0), LDS-combined stats.
// R3: XCD chunk swizzle + A-panel block ordering (FETCH 136->49.5 MB).
// R4: TRUE counted-vmcnt pipeline (T3/T4): __syncthreads() per K-tile forced vmcnt(0) drains of
//     the just-issued prefetch (MfmaUtil stuck at 33% = pure latency stall). Now BK=32, 4-buffer
//     LDS ring, stage issued 3 tiles ahead, tile boundary = sched_barrier + s_waitcnt vmcnt(8) +
//     raw s_barrier (never vmcnt(0) in main loop; tail peels 8->4->0).

typedef __attribute__((ext_vector_type(8))) _Float16 f16x8;
typedef __attribute__((ext_vector_type(4))) float f32x4;

#define EPSLN 1e-5f
#define HDIM 1024

__device__ __forceinline__ void gload16(const void* g, void* l) {
  __builtin_amdgcn_global_load_lds(
      (const __attribute__((address_space(1))) unsigned int*)g,
      (__attribute__((address_space(3))) unsigned int*)l, 16, 0, 0);
}

// ---------------- zero stats ----------------
__global__ __launch_bounds__(256) void zero_f32(float* __restrict__ p, int n) {
  int i = blockIdx.x * 256 + threadIdx.x;
  if (i < n) p[i] = 0.f;
}

// ---------------- fold block weights ----------------
__global__ __launch_bounds__(256) void fold_blk(
    const float* __restrict__ bg, const float* __restrict__ bb,
    const float* __restrict__ bw, const float* __restrict__ bbias,
    _Float16* __restrict__ Wf, float* __restrict__ bfold, float* __restrict__ Sfold) {
  int lo = blockIdx.x;            // layer*1024 + o
  int layer = lo >> 10;
  const float* wrow = bw + (size_t)lo * HDIM;
  const float* g = bg + (size_t)layer * HDIM;
  const float* be = bb + (size_t)layer * HDIM;
  _Float16* wout = Wf + (size_t)lo * HDIM;
  int t = threadIdx.x;
  float s = 0.f, acb = 0.f;
  for (int i = t; i < HDIM; i += 256) {
    float wv = wrow[i];
    _Float16 wp = (_Float16)(wv * g[i]);
    wout[i] = wp;
    s += (float)wp;               // S' from ROUNDED weights (consistency with GEMM)
    acb += be[i] * wv;
  }
#pragma unroll
  for (int off = 1; off < 64; off <<= 1) { s += __shfl_xor(s, off); acb += __shfl_xor(acb, off); }
  __shared__ float rs[4], rb[4];
  int l = t & 63, w = t >> 6;
  if (l == 0) { rs[w] = s; rb[w] = acb; }
  __syncthreads();
  if (t == 0) {
    Sfold[lo] = rs[0] + rs[1] + rs[2] + rs[3];
    bfold[lo] = bbias[lo] + rb[0] + rb[1] + rb[2] + rb[3];
  }
}

// ---------------- fold head ----------------
__global__ __launch_bounds__(256) void fold_head(
    const float* __restrict__ lg, const float* __restrict__ lb,
    const float* __restrict__ lw, const float* __restrict__ lbias,
    float* __restrict__ headW, float* __restrict__ headAux) {
  int t = threadIdx.x;
  float s = 0.f, acb = 0.f;
  for (int i = t; i < HDIM; i += 256) {
    float wp = lw[i] * lg[i];
    headW[i] = wp;
    s += wp;
    acb += lb[i] * lw[i];
  }
#pragma unroll
  for (int off = 1; off < 64; off <<= 1) { s += __shfl_xor(s, off); acb += __shfl_xor(acb, off); }
  __shared__ float rs[4], rb[4];
  int l = t & 63, w = t >> 6;
  if (l == 0) { rs[w] = s; rb[w] = acb; }
  __syncthreads();
  if (t == 0) {
    headAux[0] = rs[0] + rs[1] + rs[2] + rs[3];
    headAux[1] = lbias[0] + rb[0] + rb[1] + rb[2] + rb[3];
  }
}

// ---------------- stem weight pad+cast ----------------
__global__ __launch_bounds__(256) void fold_stem(const float* __restrict__ stw,
                                                 _Float16* __restrict__ Wst) {
  int idx = blockIdx.x * 256 + threadIdx.x;   // 1024*64
  int o = idx >> 6, i = idx & 63;
  Wst[idx] = (i < 26) ? (_Float16)stw[o * 26 + i] : (_Float16)0.f;
}

// ---------------- stem prepass: LN(26) -> xn fp16 [rows][64], zero-padded; 256 rows/block ----------------
__global__ __launch_bounds__(256) void stem_prep(
    const float* __restrict__ x, const float* __restrict__ stg, const float* __restrict__ stb,
    _Float16* __restrict__ xn, int rowBase) {
  __shared__ float xin[256 * 26];
  __shared__ _Float16 xo[256 * 64];
  int t = threadIdx.x;
  const float* src = x + ((size_t)rowBase + (size_t)blockIdx.x * 256) * 26;
  for (int i = t; i < 256 * 26; i += 256) xin[i] = src[i];
  __syncthreads();
  {
    float m = 0.f;
#pragma unroll
    for (int i = 0; i < 26; ++i) m += xin[t * 26 + i];
    m *= (1.f / 26.f);
    float v = 0.f;
#pragma unroll
    for (int i = 0; i < 26; ++i) { float d = xin[t * 26 + i] - m; v += d * d; }
    float rstd = rsqrtf(v * (1.f / 26.f) + EPSLN);
    _Float16* orow = xo + t * 64;
#pragma unroll
    for (int i = 0; i < 26; ++i)
      orow[i] = (_Float16)((xin[t * 26 + i] - m) * rstd * stg[i] + stb[i]);
#pragma unroll
    for (int i = 26; i < 64; ++i) orow[i] = (_Float16)0.f;
  }
  __syncthreads();
  const float4* s4 = (const float4*)xo;                       // 2048 vec4
  float4* d4 = (float4*)(xn + (size_t)blockIdx.x * 256 * 64);
  for (int i = t; i < 2048; i += 256) d4[i] = s4[i];
}

// ---------------- stem GEMM: h0 = relu(xn @ Wst^T + stbias), K=64, + stats (LDS-combined) ----------------
__global__ __launch_bounds__(256) void stem_gemm(
    const _Float16* __restrict__ xn, const _Float16* __restrict__ Wst,
    const float* __restrict__ stbias, _Float16* __restrict__ hout,
    float* __restrict__ stats_out) {
  __shared__ _Float16 As[128 * 64];
  __shared__ _Float16 Bs[128 * 64];
  const int t = threadIdx.x;
  const int l = t & 63;
  const int w = t >> 6;
  const int wm = w >> 1, wn = w & 1;
  const int brow = blockIdx.x * 128;
  const int bcol = blockIdx.y * 128;

  f32x4 acc[4][4];
#pragma unroll
  for (int i = 0; i < 4; ++i)
#pragma unroll
    for (int j = 0; j < 4; ++j) acc[i][j] = (f32x4){0.f, 0.f, 0.f, 0.f};

  const _Float16* ga = xn + (size_t)(brow + (t >> 3)) * 64 + (t & 7) * 8;
  const _Float16* gb = Wst + (size_t)(bcol + (t >> 3)) * 64 + (t & 7) * 8;
  char* lA = (char*)As + (size_t)w * 1024;
  char* lB = (char*)Bs + (size_t)w * 1024;
#pragma unroll
  for (int q = 0; q < 4; ++q) {
    gload16(ga + (size_t)q * 32 * 64, lA + q * 4096);
    gload16(gb + (size_t)q * 32 * 64, lB + q * 4096);
  }
  __syncthreads();

  const int abyte0 = (wm * 64 + (l & 15)) * 128 + (l >> 4) * 16;
  const int bbyte0 = (wn * 64 + (l & 15)) * 128 + (l >> 4) * 16;
#pragma unroll
  for (int ks = 0; ks < 2; ++ks) {
    f16x8 af[4], bfr[4];
#pragma unroll
    for (int m = 0; m < 4; ++m)
      af[m] = *(const f16x8*)((const char*)As + abyte0 + m * 2048 + ks * 64);
#pragma unroll
    for (int n = 0; n < 4; ++n)
      bfr[n] = *(const f16x8*)((const char*)Bs + bbyte0 + n * 2048 + ks * 64);
#pragma unroll
    for (int m = 0; m < 4; ++m)
#pragma unroll
      for (int n = 0; n < 4; ++n)
        acc[m][n] = __builtin_amdgcn_mfma_f32_16x16x32_f16(af[m], bfr[n], acc[m][n], 0, 0, 0);
  }

  __syncthreads();               // done with As; reuse as stats scratch
  float* sred = (float*)As;      // 128 rows x {sum,sumsq}
  sred[t] = 0.f;                 // 256 threads cover 256 floats
  __syncthreads();

  float Bf[4];
#pragma unroll
  for (int n = 0; n < 4; ++n) Bf[n] = stbias[bcol + wn * 64 + n * 16 + (l & 15)];
#pragma unroll
  for (int m = 0; m < 4; ++m) {
#pragma unroll
    for (int rg = 0; rg < 4; ++rg) {
      int rloc = wm * 64 + m * 16 + (l >> 4) * 4 + rg;
      int lrow = brow + rloc;
      float ps = 0.f, psq = 0.f;
#pragma unroll
      for (int n = 0; n < 4; ++n) {
        int col = bcol + wn * 64 + n * 16 + (l & 15);
        float vv = fmaxf(acc[m][n][rg] + Bf[n], 0.f);
        hout[(size_t)lrow * HDIM + col] = (_Float16)vv;
        ps += vv; psq += vv * vv;
      }
#pragma unroll
      for (int off = 1; off < 16; off <<= 1) {
        ps += __shfl_xor(ps, off);
        psq += __shfl_xor(psq, off);
      }
      if ((l & 15) == 0) {
        atomicAdd(&sred[rloc * 2 + 0], ps);
        atomicAdd(&sred[rloc * 2 + 1], psq);
      }
    }
  }
  __syncthreads();
  atomicAdd(&stats_out[(size_t)(brow + (t >> 1)) * 2 + (t & 1)], sred[t]);
}

// ---------------- per-layer fused GEMM, 256x256, BK=32, 4-buffer counted-vmcnt ring ----------------
// 512 thr = 8 waves (2M x 4N); per-wave 128x64 output = acc[8][4]; 32 MFMA(16x16x32 f16)/wave/tile.
// LDS: 4 ring buffers x (A 16KB | B 16KB) = 128KB. Stage issued 3 tiles ahead; tile boundary is
// sched_barrier + s_waitcnt vmcnt(8) + raw s_barrier (per-wave count: {kt+2,kt+3} stay in flight,
// so stage(kt+1) is guaranteed landed; barrier extends that to all waves). Never vmcnt(0) in the
// main loop -- the m97 barrier-drain stall is gone. Tail peels vmcnt 8->4->0.
// Swizzle (64B rows): stored chunk s holds global k-chunk s^(row&3); reads XOR the same -> all
// 32 banks perfectly balanced for ds_read_b128 (verified-zero-conflict pattern class from R2/R3).
__global__ __launch_bounds__(512, 2) void layer_gemm(
    const _Float16* __restrict__ hin, const float* __restrict__ stats_in,
    const _Float16* __restrict__ W, const float* __restrict__ bfold,
    const float* __restrict__ Sfold, _Float16* __restrict__ hout,
    float* __restrict__ stats_out) {
  __shared__ __align__(128) char smem[4 * 32768];  // ring: [buf][A 16KB | B 16KB]
  const int t = threadIdx.x;
  const int l = t & 63;
  const int w = t >> 6;
  const int wm = w >> 2, wn = w & 3;
  int bid = blockIdx.x;
  {  // XCD chunk swizzle: contiguous bid range per XCD (A-panel groups share one L2)
    int nb = gridDim.x;
    if ((nb & 7) == 0) { int cpx = nb >> 3; bid = (bid & 7) * cpx + (bid >> 3); }
  }
  const int brow = (bid >> 2) * 256;   // consecutive bids share the A-panel
  const int bcol = (bid & 3) * 256;

  f32x4 acc[8][4];
#pragma unroll
  for (int i = 0; i < 8; ++i)
#pragma unroll
    for (int j = 0; j < 4; ++j) acc[i][j] = (f32x4){0.f, 0.f, 0.f, 0.f};

  // staging: per tile each thread does 2xA + 2xB gload16. Thread t covers row t>>2 (+128 for
  // second issue), source chunk pre-swizzled: cswz = (t&3) ^ (row&3).
  const int cswz = (t & 3) ^ ((t >> 2) & 3);
  const _Float16* gA = hin + (size_t)(brow + (t >> 2)) * HDIM + cswz * 8;
  const _Float16* gB = W + (size_t)(bcol + (t >> 2)) * HDIM + cswz * 8;
  const int dstw = w << 10;  // wave-uniform LDS dest offset (lane adds l*16)

  auto stage = [&](int kt) {
    char* dA = smem + (kt & 3) * 32768 + dstw;
    const _Float16* sA = gA + kt * 32;
    const _Float16* sB = gB + kt * 32;
    gload16(sA, dA);
    gload16(sA + (size_t)128 * HDIM, dA + 8192);
    gload16(sB, dA + 16384);
    gload16(sB + (size_t)128 * HDIM, dA + 24576);
  };

  // ds_read bases: row*64 + (chunk ^ (row&3))*16; row&3 == l&3 for every frag row
  const int cxk = (((l >> 4) ^ (l & 3)) << 4);
  const int arow0 = wm * 8192 + (l & 15) * 64 + cxk;
  const int brow0 = 16384 + wn * 4096 + (l & 15) * 64 + cxk;

  auto tile = [&](int kt, bool do_stage) {
    const char* bc = smem + (kt & 3) * 32768;
    f16x8 bf[4], af[8];
#pragma unroll
    for (int n = 0; n < 4; ++n) bf[n] = *(const f16x8*)(bc + brow0 + n * 1024);
#pragma unroll
    for (int m = 0; m < 8; ++m) af[m] = *(const f16x8*)(bc + arow0 + m * 1024);
    if (do_stage) stage(kt + 3);
    __builtin_amdgcn_s_setprio(1);
#pragma unroll
    for (int m = 0; m < 8; ++m)
#pragma unroll
      for (int n = 0; n < 4; ++n)
        acc[m][n] = __builtin_amdgcn_mfma_f32_16x16x32_f16(af[m], bf[n], acc[m][n], 0, 0, 0);
    __builtin_amdgcn_s_setprio(0);
  };

#define TILE_BARRIER(N)                                      \
  do {                                                       \
    __builtin_amdgcn_sched_barrier(0);                       \
    asm volatile("s_waitcnt vmcnt(" #N ")" ::: "memory");    \
    __builtin_amdgcn_s_barrier();                            \
    __builtin_amdgcn_sched_barrier(0);                       \
  } while (0)

  // prologue: stage tiles 0..2
  stage(0);
  stage(1);
  stage(2);
  TILE_BARRIER(8);   // own stage(0) landed; barrier -> everyone's did

#pragma unroll 1
  for (int kt = 0; kt < 29; ++kt) {
    tile(kt, true);  // stages kt+3
    TILE_BARRIER(8); // {kt+2, kt+3} in flight; stage(kt+1) landed
  }
  tile(29, false);
  TILE_BARRIER(4);
  tile(30, false);
  TILE_BARRIER(0);
  tile(31, false);
  __syncthreads();   // full drain before LDS reuse
#undef TILE_BARRIER

  // ---- epilogue: LN-affine + relu + fp16 store; stats combined in LDS, then 1 atomic/row-val ----
  float* sred = (float*)smem;  // 256 rows x {sum, sumsq}
  sred[t] = 0.f;               // 512 threads cover 512 floats
  __syncthreads();

  float Sf[4], Bf2[4];
#pragma unroll
  for (int n = 0; n < 4; ++n) {
    int col = bcol + wn * 64 + n * 16 + (l & 15);
    Sf[n] = Sfold[col];
    Bf2[n] = bfold[col];
  }
#pragma unroll
  for (int m = 0; m < 8; ++m) {
#pragma unroll
    for (int rg = 0; rg < 4; ++rg) {
      int rloc = wm * 128 + m * 16 + (l >> 4) * 4 + rg;  // C/D: col=lane&15, row=(lane>>4)*4+reg
      int grow = brow + rloc;
      float sum = stats_in[(size_t)grow * 2 + 0];
      float sumsq = stats_in[(size_t)grow * 2 + 1];
      float mean = sum * (1.f / 1024.f);
      float rstd = rsqrtf(sumsq * (1.f / 1024.f) - mean * mean + EPSLN);
      float ps = 0.f, psq = 0.f;
#pragma unroll
      for (int n = 0; n < 4; ++n) {
        int col = bcol + wn * 64 + n * 16 + (l & 15);
        float vv = rstd * (acc[m][n][rg] - mean * Sf[n]) + Bf2[n];
        vv = fmaxf(vv, 0.f);
        hout[(size_t)grow * HDIM + col] = (_Float16)vv;
        ps += vv; psq += vv * vv;
      }
#pragma unroll
      for (int off2 = 1; off2 < 16; off2 <<= 1) {
        ps += __shfl_xor(ps, off2);
        psq += __shfl_xor(psq, off2);
      }
      if ((l & 15) == 0) {
        atomicAdd(&sred[rloc * 2 + 0], ps);
        atomicAdd(&sred[rloc * 2 + 1], psq);
      }
    }
  }
  __syncthreads();
  atomicAdd(&stats_out[(size_t)(brow + (t >> 1)) * 2 + (t & 1)], sred[t]);
}

// ---------------- head: out = sigmoid(rstd*(h8@W'' - mean*S'') + b''), one wave per row ----------------
__global__ __launch_bounds__(512) void head_kernel(
    const _Float16* __restrict__ h8, const float* __restrict__ stats8,
    const float* __restrict__ headW, const float* __restrict__ headAux,
    float* __restrict__ out, int rowBase) {
  int t = threadIdx.x, l = t & 63, w = t >> 6;
  int lrow = blockIdx.x * 8 + w;
  const f16x8* hp = (const f16x8*)(h8 + (size_t)lrow * HDIM) + l * 2;
  f16x8 v0 = hp[0], v1 = hp[1];
  float acc = 0.f;
#pragma unroll
  for (int j = 0; j < 8; ++j) acc += (float)v0[j] * headW[l * 16 + j];
#pragma unroll
  for (int j = 0; j < 8; ++j) acc += (float)v1[j] * headW[l * 16 + 8 + j];
#pragma unroll
  for (int off = 1; off < 64; off <<= 1) acc += __shfl_xor(acc, off);
  if (l == 0) {
    float sum = stats8[lrow * 2 + 0], sumsq = stats8[lrow * 2 + 1];
    float mean = sum * (1.f / 1024.f);
    float rstd = rsqrtf(sumsq * (1.f / 1024.f) - mean * mean + EPSLN);
    float z = rstd * (acc - mean * headAux[0]) + headAux[1];
    out[rowBase + lrow] = 1.f / (1.f + expf(-z));
  }
}

extern "C" void kernel_launch(void* const* d_in, const int* in_sizes, int n_in,
                              void* d_out, int out_size, void* d_ws, size_t ws_size,
                              hipStream_t stream) {
  const float* x      = (const float*)d_in[0];
  const float* stg    = (const float*)d_in[1];
  const float* stb    = (const float*)d_in[2];
  const float* stw    = (const float*)d_in[3];
  const float* stbias = (const float*)d_in[4];
  const float* bg     = (const float*)d_in[5];
  const float* bb     = (const float*)d_in[6];
  const float* bw     = (const float*)d_in[7];
  const float* bbias  = (const float*)d_in[8];
  const float* lg     = (const float*)d_in[9];
  const float* lb     = (const float*)d_in[10];
  const float* lw     = (const float*)d_in[11];
  const float* lbias  = (const float*)d_in[12];
  float* out = (float*)d_out;
  const int B = 65536;
  const int L = 8;

  char* ws = (char*)d_ws;
  size_t off = 0;
  auto carve = [&](size_t bytes) -> char* {
    char* p = ws + off;
    off = (off + bytes + 255) & ~(size_t)255;
    return p;
  };
  _Float16* Wf   = (_Float16*)carve((size_t)L * HDIM * HDIM * 2);
  float* bfold   = (float*)carve((size_t)L * HDIM * 4);
  float* Sfold   = (float*)carve((size_t)L * HDIM * 4);
  float* headW   = (float*)carve((size_t)HDIM * 4);
  float* headAux = (float*)carve(256);
  _Float16* Wst  = (_Float16*)carve((size_t)HDIM * 64 * 2);
  size_t fixed = off;

  // pick largest batch chunk R (power of 2, >=256) whose buffers fit in ws
  int R = B;
  while (R > 256) {
    size_t need = fixed + 2 * ((size_t)R * HDIM * 2 + 256) + ((size_t)9 * R * 2 * 4 + 256)
                  + ((size_t)R * 64 * 2 + 256);
    if (need <= ws_size) break;
    R >>= 1;
  }
  _Float16* hA = (_Float16*)carve((size_t)R * HDIM * 2);
  _Float16* hB = (_Float16*)carve((size_t)R * HDIM * 2);
  float* stats = (float*)carve((size_t)9 * R * 2 * 4);  // 9 slots: h0..h8 (sum,sumsq)
  _Float16* xnb = (_Float16*)carve((size_t)R * 64 * 2);

  fold_blk<<<L * HDIM, 256, 0, stream>>>(bg, bb, bw, bbias, Wf, bfold, Sfold);
  fold_head<<<1, 256, 0, stream>>>(lg, lb, lw, lbias, headW, headAux);
  fold_stem<<<HDIM * 64 / 256, 256, 0, stream>>>(stw, Wst);

  const int nstats = 9 * R * 2;
  for (int c = 0; c < B / R; ++c) {
    int rowBase = c * R;
    zero_f32<<<(nstats + 255) / 256, 256, 0, stream>>>(stats, nstats);
    stem_prep<<<R / 256, 256, 0, stream>>>(x, stg, stb, xnb, rowBase);
    {
      dim3 grid(R / 128, 8);
      stem_gemm<<<grid, 256, 0, stream>>>(xnb, Wst, stbias, hA, stats);
    }
    _Float16* cur = hA;
    _Float16* nxt = hB;
    for (int lyr = 0; lyr < L; ++lyr) {
      int nb = (R / 256) * 4;
      layer_gemm<<<nb, 512, 0, stream>>>(
          cur, stats + (size_t)lyr * R * 2, Wf + (size_t)lyr * HDIM * HDIM,
          bfold + lyr * HDIM, Sfold + lyr * HDIM, nxt, stats + (size_t)(lyr + 1) * R * 2);
      _Float16* tmp = cur; cur = nxt; nxt = tmp;
    }
    head_kernel<<<R / 8, 512, 0, stream>>>(cur, stats + (size_t)8 * R * 2, headW, headAux, out, rowBase);
  }
}

// Round 6
// 1395.816 us; speedup vs baseline: 1.0163x; 1.0163x over previous
//
#include <hip/hip_runtime.h>
#include <hip/hip_bf16.h>
#include <stdint.h>

// DeepFakeDetectionModel: stem LN(26)->Linear(26->1024)->ReLU, 8x [LN->Linear(1024->1024)->ReLU],
// head LN->Linear(1024->1)->sigmoid.  B=65536.
//
// LN folded into weights (W'=gamma*W fp16, S'=sum W', b'=b+beta@W^T); GEMMs run on RAW fp16
// activations; LN affine applied in epilogue from per-row (sum,sumsq) stats.
// R2: 256x256 tile, T2 swizzle (conflicts 2.5e7 -> 0), LDS-combined stats.
// R3: XCD chunk swizzle + A-panel block ordering (FETCH 136->49.5 MB).  88.2us/layer.
// R4: counted-vmcnt 4-buffer ring (BK=32) -- but swizzle bug: chunk^=(row&3) collapses onto
//     row&1 -> 4-way read conflict (6.29e6), 93.5us.
// R5: swizzle fixed to chunk^=((row>>1)&3): bank key is (row&1,chunk), now all 8 groups x2
//     lanes = free. Stem fused: LN(26) computed in-block, A written to LDS pre-swizzled via
//     ds_write_b128, Wst pre-swizzled in storage so global_load_lds lands swizzled (rule #21).
//     Kills stem_prep dispatch + xn round-trip + stem's 16-way LDS conflicts.

typedef __attribute__((ext_vector_type(8))) _Float16 f16x8;
typedef __attribute__((ext_vector_type(4))) float f32x4;

#define EPSLN 1e-5f
#define HDIM 1024

__device__ __forceinline__ void gload16(const void* g, void* l) {
  __builtin_amdgcn_global_load_lds(
      (const __attribute__((address_space(1))) unsigned int*)g,
      (__attribute__((address_space(3))) unsigned int*)l, 16, 0, 0);
}

// ---------------- zero stats ----------------
__global__ __launch_bounds__(256) void zero_f32(float* __restrict__ p, int n) {
  int i = blockIdx.x * 256 + threadIdx.x;
  if (i < n) p[i] = 0.f;
}

// ---------------- fold block weights ----------------
__global__ __launch_bounds__(256) void fold_blk(
    const float* __restrict__ bg, const float* __restrict__ bb,
    const float* __restrict__ bw, const float* __restrict__ bbias,
    _Float16* __restrict__ Wf, float* __restrict__ bfold, float* __restrict__ Sfold) {
  int lo = blockIdx.x;            // layer*1024 + o
  int layer = lo >> 10;
  const float* wrow = bw + (size_t)lo * HDIM;
  const float* g = bg + (size_t)layer * HDIM;
  const float* be = bb + (size_t)layer * HDIM;
  _Float16* wout = Wf + (size_t)lo * HDIM;
  int t = threadIdx.x;
  float s = 0.f, acb = 0.f;
  for (int i = t; i < HDIM; i += 256) {
    float wv = wrow[i];
    _Float16 wp = (_Float16)(wv * g[i]);
    wout[i] = wp;
    s += (float)wp;               // S' from ROUNDED weights (consistency with GEMM)
    acb += be[i] * wv;
  }
#pragma unroll
  for (int off = 1; off < 64; off <<= 1) { s += __shfl_xor(s, off); acb += __shfl_xor(acb, off); }
  __shared__ float rs[4], rb[4];
  int l = t & 63, w = t >> 6;
  if (l == 0) { rs[w] = s; rb[w] = acb; }
  __syncthreads();
  if (t == 0) {
    Sfold[lo] = rs[0] + rs[1] + rs[2] + rs[3];
    bfold[lo] = bbias[lo] + rb[0] + rb[1] + rb[2] + rb[3];
  }
}

// ---------------- fold head ----------------
__global__ __launch_bounds__(256) void fold_head(
    const float* __restrict__ lg, const float* __restrict__ lb,
    const float* __restrict__ lw, const float* __restrict__ lbias,
    float* __restrict__ headW, float* __restrict__ headAux) {
  int t = threadIdx.x;
  float s = 0.f, acb = 0.f;
  for (int i = t; i < HDIM; i += 256) {
    float wp = lw[i] * lg[i];
    headW[i] = wp;
    s += wp;
    acb += lb[i] * lw[i];
  }
#pragma unroll
  for (int off = 1; off < 64; off <<= 1) { s += __shfl_xor(s, off); acb += __shfl_xor(acb, off); }
  __shared__ float rs[4], rb[4];
  int l = t & 63, w = t >> 6;
  if (l == 0) { rs[w] = s; rb[w] = acb; }
  __syncthreads();
  if (t == 0) {
    headAux[0] = rs[0] + rs[1] + rs[2] + rs[3];
    headAux[1] = lbias[0] + rb[0] + rb[1] + rb[2] + rb[3];
  }
}

// ---------------- stem weight pad+cast, PRE-SWIZZLED storage ----------------
// Storage position (o, j): chunk cs=j>>3 holds global chunk cs^(o&7), i.e. global col
// i = ((j>>3)^(o&7))*8 + (j&7).  global_load_lds then lands this linearly in LDS, and the
// MFMA reads XOR the same key -> conflict-free (rule #21: same involution both sides).
__global__ __launch_bounds__(256) void fold_stem(const float* __restrict__ stw,
                                                 _Float16* __restrict__ Wst) {
  int idx = blockIdx.x * 256 + threadIdx.x;   // 1024*64
  int o = idx >> 6, j = idx & 63;
  int i = (((j >> 3) ^ (o & 7)) << 3) + (j & 7);
  Wst[idx] = (i < 26) ? (_Float16)stw[o * 26 + i] : (_Float16)0.f;
}

// ---------------- fused stem: LN(26) in-block + GEMM K=64 + bias/relu + stats ----------------
// grid (R/128, 8), 256 thr = 4 waves (2x2). A-tile built in LDS from raw x with swizzled
// ds_write_b128; B staged via gload16 from pre-swizzled Wst. Reads XOR chunk with (row&7).
__global__ __launch_bounds__(256) void stem_gemm(
    const float* __restrict__ x, const float* __restrict__ stg, const float* __restrict__ stb,
    const _Float16* __restrict__ Wst, const float* __restrict__ stbias,
    _Float16* __restrict__ hout, float* __restrict__ stats_out, int rowBase) {
  __shared__ float xin[128 * 26];
  __shared__ _Float16 As[128 * 64];
  __shared__ _Float16 Bs[128 * 64];
  const int t = threadIdx.x;
  const int l = t & 63;
  const int w = t >> 6;
  const int wm = w >> 1, wn = w & 1;
  const int brow = blockIdx.x * 128;
  const int bcol = blockIdx.y * 128;

  // stage B (async, lands swizzled because Wst storage is pre-swizzled)
  const _Float16* gb = Wst + (size_t)(bcol + (t >> 3)) * 64 + (t & 7) * 8;
  char* lB = (char*)Bs + (size_t)w * 1024;
#pragma unroll
  for (int q = 0; q < 4; ++q) gload16(gb + (size_t)q * 32 * 64, lB + q * 4096);

  // raw x rows -> LDS (coalesced)
  const float* src = x + ((size_t)rowBase + brow) * 26;
  for (int i = t; i < 128 * 26; i += 256) xin[i] = src[i];
  __syncthreads();

  // LN per row (threads 0..127), write A-tile swizzled: chunk c stored at c^(row&7)
  if (t < 128) {
    float m = 0.f;
#pragma unroll
    for (int i = 0; i < 26; ++i) m += xin[t * 26 + i];
    m *= (1.f / 26.f);
    float v = 0.f;
#pragma unroll
    for (int i = 0; i < 26; ++i) { float d = xin[t * 26 + i] - m; v += d * d; }
    float rstd = rsqrtf(v * (1.f / 26.f) + EPSLN);
    _Float16 tmp[32];
#pragma unroll
    for (int i = 0; i < 26; ++i)
      tmp[i] = (_Float16)((xin[t * 26 + i] - m) * rstd * stg[i] + stb[i]);
#pragma unroll
    for (int i = 26; i < 32; ++i) tmp[i] = (_Float16)0.f;
    char* arow = (char*)As + t * 128;
#pragma unroll
    for (int c = 0; c < 4; ++c) {   // chunks 0..3 hold cols 0..31; 4..7 are zero
      f16x8 vv;
#pragma unroll
      for (int j = 0; j < 8; ++j) vv[j] = tmp[c * 8 + j];
      *(f16x8*)(arow + ((c ^ (t & 7)) << 4)) = vv;
    }
    f16x8 vz = (f16x8)(_Float16)0.f;
#pragma unroll
    for (int c = 4; c < 8; ++c) *(f16x8*)(arow + ((c ^ (t & 7)) << 4)) = vz;
  }
  __syncthreads();  // drains vmcnt (B staged) + lgkm (A written)

  f32x4 acc[4][4];
#pragma unroll
  for (int i = 0; i < 4; ++i)
#pragma unroll
    for (int j = 0; j < 4; ++j) acc[i][j] = (f32x4){0.f, 0.f, 0.f, 0.f};

#pragma unroll
  for (int ks = 0; ks < 2; ++ks) {
    const int cx = ((ks * 4 + (l >> 4)) ^ (l & 7)) << 4;
    f16x8 af[4], bfr[4];
#pragma unroll
    for (int m = 0; m < 4; ++m)
      af[m] = *(const f16x8*)((const char*)As + (wm * 64 + m * 16 + (l & 15)) * 128 + cx);
#pragma unroll
    for (int n = 0; n < 4; ++n)
      bfr[n] = *(const f16x8*)((const char*)Bs + (wn * 64 + n * 16 + (l & 15)) * 128 + cx);
#pragma unroll
    for (int m = 0; m < 4; ++m)
#pragma unroll
      for (int n = 0; n < 4; ++n)
        acc[m][n] = __builtin_amdgcn_mfma_f32_16x16x32_f16(af[m], bfr[n], acc[m][n], 0, 0, 0);
  }

  __syncthreads();               // done with xin; reuse as stats scratch
  float* sred = (float*)xin;     // 128 rows x {sum,sumsq}
  if (t < 256) sred[t] = 0.f;
  __syncthreads();

  float Bf[4];
#pragma unroll
  for (int n = 0; n < 4; ++n) Bf[n] = stbias[bcol + wn * 64 + n * 16 + (l & 15)];
#pragma unroll
  for (int m = 0; m < 4; ++m) {
#pragma unroll
    for (int rg = 0; rg < 4; ++rg) {
      int rloc = wm * 64 + m * 16 + (l >> 4) * 4 + rg;
      int lrow = brow + rloc;
      float ps = 0.f, psq = 0.f;
#pragma unroll
      for (int n = 0; n < 4; ++n) {
        int col = bcol + wn * 64 + n * 16 + (l & 15);
        float vv = fmaxf(acc[m][n][rg] + Bf[n], 0.f);
        hout[(size_t)lrow * HDIM + col] = (_Float16)vv;
        ps += vv; psq += vv * vv;
      }
#pragma unroll
      for (int off = 1; off < 16; off <<= 1) {
        ps += __shfl_xor(ps, off);
        psq += __shfl_xor(psq, off);
      }
      if ((l & 15) == 0) {
        atomicAdd(&sred[rloc * 2 + 0], ps);
        atomicAdd(&sred[rloc * 2 + 1], psq);
      }
    }
  }
  __syncthreads();
  if (t < 256) atomicAdd(&stats_out[(size_t)(brow + (t >> 1)) * 2 + (t & 1)], sred[t]);
}

// ---------------- per-layer fused GEMM, 256x256, BK=32, 4-buffer counted-vmcnt ring ----------------
// 512 thr = 8 waves (2M x 4N); per-wave 128x64 output = acc[8][4]; 32 MFMA/wave/tile.
// LDS: 4 ring buffers x (A 16KB | B 16KB) = 128KB. Stage 3 tiles ahead; tile boundary =
// sched_barrier + s_waitcnt vmcnt(8) + s_barrier (never vmcnt(0) in main loop; tail 8->4->0).
// Swizzle (64B rows, bank key = (row&1,chunk)): stored chunk = nominal ^ ((row>>1)&3) ->
// 16 lanes spread over all 8 four-bank groups x2 = free (R4's row&3 was 4-way conflicted).
__global__ __launch_bounds__(512, 2) void layer_gemm(
    const _Float16* __restrict__ hin, const float* __restrict__ stats_in,
    const _Float16* __restrict__ W, const float* __restrict__ bfold,
    const float* __restrict__ Sfold, _Float16* __restrict__ hout,
    float* __restrict__ stats_out) {
  __shared__ __align__(128) char smem[4 * 32768];  // ring: [buf][A 16KB | B 16KB]
  const int t = threadIdx.x;
  const int l = t & 63;
  const int w = t >> 6;
  const int wm = w >> 2, wn = w & 3;
  int bid = blockIdx.x;
  {  // XCD chunk swizzle: contiguous bid range per XCD (A-panel groups share one L2)
    int nb = gridDim.x;
    if ((nb & 7) == 0) { int cpx = nb >> 3; bid = (bid & 7) * cpx + (bid >> 3); }
  }
  const int brow = (bid >> 2) * 256;   // consecutive bids share the A-panel
  const int bcol = (bid & 3) * 256;

  f32x4 acc[8][4];
#pragma unroll
  for (int i = 0; i < 8; ++i)
#pragma unroll
    for (int j = 0; j < 4; ++j) acc[i][j] = (f32x4){0.f, 0.f, 0.f, 0.f};

  // staging: thread t covers row t>>2 (and +128), stored chunk (t&3) must hold global chunk
  // (t&3) ^ f(row), f(r)=(r>>1)&3 -> source chunk cswz = (t&3) ^ ((t>>3)&3).
  const int cswz = (t & 3) ^ ((t >> 3) & 3);
  const _Float16* gA = hin + (size_t)(brow + (t >> 2)) * HDIM + cswz * 8;
  const _Float16* gB = W + (size_t)(bcol + (t >> 2)) * HDIM + cswz * 8;
  const int dstw = w << 10;  // wave-uniform LDS dest offset (lane adds l*16)

  auto stage = [&](int kt) {
    char* dA = smem + (kt & 3) * 32768 + dstw;
    const _Float16* sA = gA + kt * 32;
    const _Float16* sB = gB + kt * 32;
    gload16(sA, dA);
    gload16(sA + (size_t)128 * HDIM, dA + 8192);
    gload16(sB, dA + 16384);
    gload16(sB + (size_t)128 * HDIM, dA + 24576);
  };

  // ds_read: row r, nominal chunk l>>4 -> read chunk (l>>4) ^ ((r>>1)&3); r>>1&3 =
  // ((l&15)>>1)&3 for every frag row (m*16, wm*128, wn*64 contribute 0 mod 4 after >>1).
  const int cxk = (((l >> 4) ^ (((l & 15) >> 1) & 3)) << 4);
  const int arow0 = wm * 8192 + (l & 15) * 64 + cxk;
  const int brow0 = 16384 + wn * 4096 + (l & 15) * 64 + cxk;

  auto tile = [&](int kt, bool do_stage) {
    const char* bc = smem + (kt & 3) * 32768;
    f16x8 bf[4], af[8];
#pragma unroll
    for (int n = 0; n < 4; ++n) bf[n] = *(const f16x8*)(bc + brow0 + n * 1024);
#pragma unroll
    for (int m = 0; m < 8; ++m) af[m] = *(const f16x8*)(bc + arow0 + m * 1024);
    if (do_stage) stage(kt + 3);
    __builtin_amdgcn_s_setprio(1);
#pragma unroll
    for (int m = 0; m < 8; ++m)
#pragma unroll
      for (int n = 0; n < 4; ++n)
        acc[m][n] = __builtin_amdgcn_mfma_f32_16x16x32_f16(af[m], bf[n], acc[m][n], 0, 0, 0);
    __builtin_amdgcn_s_setprio(0);
  };

#define TILE_BARRIER(N)                                      \
  do {                                                       \
    __builtin_amdgcn_sched_barrier(0);                       \
    asm volatile("s_waitcnt vmcnt(" #N ")" ::: "memory");    \
    __builtin_amdgcn_s_barrier();                            \
    __builtin_amdgcn_sched_barrier(0);                       \
  } while (0)

  // prologue: stage tiles 0..2
  stage(0);
  stage(1);
  stage(2);
  TILE_BARRIER(8);   // own stage(0) landed; barrier -> everyone's did

#pragma unroll 1
  for (int kt = 0; kt < 29; ++kt) {
    tile(kt, true);  // stages kt+3
    TILE_BARRIER(8); // {kt+2, kt+3} in flight; stage(kt+1) landed
  }
  tile(29, false);
  TILE_BARRIER(4);
  tile(30, false);
  TILE_BARRIER(0);
  tile(31, false);
  __syncthreads();   // full drain before LDS reuse
#undef TILE_BARRIER

  // ---- epilogue: LN-affine + relu + fp16 store; stats combined in LDS, then 1 atomic/row-val ----
  float* sred = (float*)smem;  // 256 rows x {sum, sumsq}
  sred[t] = 0.f;               // 512 threads cover 512 floats
  __syncthreads();

  float Sf[4], Bf2[4];
#pragma unroll
  for (int n = 0; n < 4; ++n) {
    int col = bcol + wn * 64 + n * 16 + (l & 15);
    Sf[n] = Sfold[col];
    Bf2[n] = bfold[col];
  }
#pragma unroll
  for (int m = 0; m < 8; ++m) {
#pragma unroll
    for (int rg = 0; rg < 4; ++rg) {
      int rloc = wm * 128 + m * 16 + (l >> 4) * 4 + rg;  // C/D: col=lane&15, row=(lane>>4)*4+reg
      int grow = brow + rloc;
      float sum = stats_in[(size_t)grow * 2 + 0];
      float sumsq = stats_in[(size_t)grow * 2 + 1];
      float mean = sum * (1.f / 1024.f);
      float rstd = rsqrtf(sumsq * (1.f / 1024.f) - mean * mean + EPSLN);
      float ps = 0.f, psq = 0.f;
#pragma unroll
      for (int n = 0; n < 4; ++n) {
        int col = bcol + wn * 64 + n * 16 + (l & 15);
        float vv = rstd * (acc[m][n][rg] - mean * Sf[n]) + Bf2[n];
        vv = fmaxf(vv, 0.f);
        hout[(size_t)grow * HDIM + col] = (_Float16)vv;
        ps += vv; psq += vv * vv;
      }
#pragma unroll
      for (int off2 = 1; off2 < 16; off2 <<= 1) {
        ps += __shfl_xor(ps, off2);
        psq += __shfl_xor(psq, off2);
      }
      if ((l & 15) == 0) {
        atomicAdd(&sred[rloc * 2 + 0], ps);
        atomicAdd(&sred[rloc * 2 + 1], psq);
      }
    }
  }
  __syncthreads();
  atomicAdd(&stats_out[(size_t)(brow + (t >> 1)) * 2 + (t & 1)], sred[t]);
}

// ---------------- head: out = sigmoid(rstd*(h8@W'' - mean*S'') + b''), one wave per row ----------------
__global__ __launch_bounds__(512) void head_kernel(
    const _Float16* __restrict__ h8, const float* __restrict__ stats8,
    const float* __restrict__ headW, const float* __restrict__ headAux,
    float* __restrict__ out, int rowBase) {
  int t = threadIdx.x, l = t & 63, w = t >> 6;
  int lrow = blockIdx.x * 8 + w;
  const f16x8* hp = (const f16x8*)(h8 + (size_t)lrow * HDIM) + l * 2;
  f16x8 v0 = hp[0], v1 = hp[1];
  float acc = 0.f;
#pragma unroll
  for (int j = 0; j < 8; ++j) acc += (float)v0[j] * headW[l * 16 + j];
#pragma unroll
  for (int j = 0; j < 8; ++j) acc += (float)v1[j] * headW[l * 16 + 8 + j];
#pragma unroll
  for (int off = 1; off < 64; off <<= 1) acc += __shfl_xor(acc, off);
  if (l == 0) {
    float sum = stats8[lrow * 2 + 0], sumsq = stats8[lrow * 2 + 1];
    float mean = sum * (1.f / 1024.f);
    float rstd = rsqrtf(sumsq * (1.f / 1024.f) - mean * mean + EPSLN);
    float z = rstd * (acc - mean * headAux[0]) + headAux[1];
    out[rowBase + lrow] = 1.f / (1.f + expf(-z));
  }
}

extern "C" void kernel_launch(void* const* d_in, const int* in_sizes, int n_in,
                              void* d_out, int out_size, void* d_ws, size_t ws_size,
                              hipStream_t stream) {
  const float* x      = (const float*)d_in[0];
  const float* stg    = (const float*)d_in[1];
  const float* stb    = (const float*)d_in[2];
  const float* stw    = (const float*)d_in[3];
  const float* stbias = (const float*)d_in[4];
  const float* bg     = (const float*)d_in[5];
  const float* bb     = (const float*)d_in[6];
  const float* bw     = (const float*)d_in[7];
  const float* bbias  = (const float*)d_in[8];
  const float* lg     = (const float*)d_in[9];
  const float* lb     = (const float*)d_in[10];
  const float* lw     = (const float*)d_in[11];
  const float* lbias  = (const float*)d_in[12];
  float* out = (float*)d_out;
  const int B = 65536;
  const int L = 8;

  char* ws = (char*)d_ws;
  size_t off = 0;
  auto carve = [&](size_t bytes) -> char* {
    char* p = ws + off;
    off = (off + bytes + 255) & ~(size_t)255;
    return p;
  };
  _Float16* Wf   = (_Float16*)carve((size_t)L * HDIM * HDIM * 2);
  float* bfold   = (float*)carve((size_t)L * HDIM * 4);
  float* Sfold   = (float*)carve((size_t)L * HDIM * 4);
  float* headW   = (float*)carve((size_t)HDIM * 4);
  float* headAux = (float*)carve(256);
  _Float16* Wst  = (_Float16*)carve((size_t)HDIM * 64 * 2);
  size_t fixed = off;

  // pick largest batch chunk R (power of 2, >=256) whose buffers fit in ws
  int R = B;
  while (R > 256) {
    size_t need = fixed + 2 * ((size_t)R * HDIM * 2 + 256) + ((size_t)9 * R * 2 * 4 + 256);
    if (need <= ws_size) break;
    R >>= 1;
  }
  _Float16* hA = (_Float16*)carve((size_t)R * HDIM * 2);
  _Float16* hB = (_Float16*)carve((size_t)R * HDIM * 2);
  float* stats = (float*)carve((size_t)9 * R * 2 * 4);  // 9 slots: h0..h8 (sum,sumsq)

  fold_blk<<<L * HDIM, 256, 0, stream>>>(bg, bb, bw, bbias, Wf, bfold, Sfold);
  fold_head<<<1, 256, 0, stream>>>(lg, lb, lw, lbias, headW, headAux);
  fold_stem<<<HDIM * 64 / 256, 256, 0, stream>>>(stw, Wst);

  const int nstats = 9 * R * 2;
  for (int c = 0; c < B / R; ++c) {
    int rowBase = c * R;
    zero_f32<<<(nstats + 255) / 256, 256, 0, stream>>>(stats, nstats);
    {
      dim3 grid(R / 128, 8);
      stem_gemm<<<grid, 256, 0, stream>>>(x, stg, stb, Wst, stbias, hA, stats, rowBase);
    }
    _Float16* cur = hA;
    _Float16* nxt = hB;
    for (int lyr = 0; lyr < L; ++lyr) {
      int nb = (R / 256) * 4;
      layer_gemm<<<nb, 512, 0, stream>>>(
          cur, stats + (size_t)lyr * R * 2, Wf + (size_t)lyr * HDIM * HDIM,
          bfold + lyr * HDIM, Sfold + lyr * HDIM, nxt, stats + (size_t)(lyr + 1) * R * 2);
      _Float16* tmp = cur; cur = nxt; nxt = tmp;
    }
    head_kernel<<<R / 8, 512, 0, stream>>>(cur, stats + (size_t)8 * R * 2, headW, headAux, out, rowBase);
  }
}

// Round 7
// 1357.042 us; speedup vs baseline: 1.0453x; 1.0286x over previous
//
#include <hip/hip_runtime.h>
#include <hip/hip_bf16.h>
#include <stdint.h>

// DeepFakeDetectionModel: stem LN(26)->Linear(26->1024)->ReLU, 8x [LN->Linear(1024->1024)->ReLU],
// head LN->Linear(1024->1)->sigmoid.  B=65536.
//
// LN folded into weights (W'=gamma*W fp16, S'=sum W', b'=b+beta@W^T); GEMMs run on RAW fp16
// activations; LN affine applied in epilogue from per-row (sum,sumsq) stats.
// R2: 256x256 tile, T2 swizzle (conflicts 2.5e7 -> 0). R3: XCD swizzle (FETCH 136->49.5MB).
// R4/R5: counted-vmcnt ring experiments -> 753 TF plateau (bulk-read single-barrier tile:
//     barrier-synced waves stall together on the read burst; 2 waves/SIMD has no filler).
// R6: m201-class 4-phase/K-tile schedule. Phases = C-quadrants (mh,nh); reads 12/4/8/0 b128 +
//     16 MFMA + 1 trailing barrier each. Stage(kt+2) into the SAME buffer, pieces issued the
//     phase after their region's last read (P1:A-evenhalves, P2:B-lo, P3:B-hi+A-oddhalves).
//     Tile boundary = vmcnt(8)+barrier (stage(kt+1) proven landed); vmcnt(0) only at tail.

typedef __attribute__((ext_vector_type(8))) _Float16 f16x8;
typedef __attribute__((ext_vector_type(4))) float f32x4;

#define EPSLN 1e-5f
#define HDIM 1024

__device__ __forceinline__ void gload16(const void* g, void* l) {
  __builtin_amdgcn_global_load_lds(
      (const __attribute__((address_space(1))) unsigned int*)g,
      (__attribute__((address_space(3))) unsigned int*)l, 16, 0, 0);
}

// ---------------- zero stats ----------------
__global__ __launch_bounds__(256) void zero_f32(float* __restrict__ p, int n) {
  int i = blockIdx.x * 256 + threadIdx.x;
  if (i < n) p[i] = 0.f;
}

// ---------------- fold block weights ----------------
__global__ __launch_bounds__(256) void fold_blk(
    const float* __restrict__ bg, const float* __restrict__ bb,
    const float* __restrict__ bw, const float* __restrict__ bbias,
    _Float16* __restrict__ Wf, float* __restrict__ bfold, float* __restrict__ Sfold) {
  int lo = blockIdx.x;            // layer*1024 + o
  int layer = lo >> 10;
  const float* wrow = bw + (size_t)lo * HDIM;
  const float* g = bg + (size_t)layer * HDIM;
  const float* be = bb + (size_t)layer * HDIM;
  _Float16* wout = Wf + (size_t)lo * HDIM;
  int t = threadIdx.x;
  float s = 0.f, acb = 0.f;
  for (int i = t; i < HDIM; i += 256) {
    float wv = wrow[i];
    _Float16 wp = (_Float16)(wv * g[i]);
    wout[i] = wp;
    s += (float)wp;               // S' from ROUNDED weights (consistency with GEMM)
    acb += be[i] * wv;
  }
#pragma unroll
  for (int off = 1; off < 64; off <<= 1) { s += __shfl_xor(s, off); acb += __shfl_xor(acb, off); }
  __shared__ float rs[4], rb[4];
  int l = t & 63, w = t >> 6;
  if (l == 0) { rs[w] = s; rb[w] = acb; }
  __syncthreads();
  if (t == 0) {
    Sfold[lo] = rs[0] + rs[1] + rs[2] + rs[3];
    bfold[lo] = bbias[lo] + rb[0] + rb[1] + rb[2] + rb[3];
  }
}

// ---------------- fold head ----------------
__global__ __launch_bounds__(256) void fold_head(
    const float* __restrict__ lg, const float* __restrict__ lb,
    const float* __restrict__ lw, const float* __restrict__ lbias,
    float* __restrict__ headW, float* __restrict__ headAux) {
  int t = threadIdx.x;
  float s = 0.f, acb = 0.f;
  for (int i = t; i < HDIM; i += 256) {
    float wp = lw[i] * lg[i];
    headW[i] = wp;
    s += wp;
    acb += lb[i] * lw[i];
  }
#pragma unroll
  for (int off = 1; off < 64; off <<= 1) { s += __shfl_xor(s, off); acb += __shfl_xor(acb, off); }
  __shared__ float rs[4], rb[4];
  int l = t & 63, w = t >> 6;
  if (l == 0) { rs[w] = s; rb[w] = acb; }
  __syncthreads();
  if (t == 0) {
    headAux[0] = rs[0] + rs[1] + rs[2] + rs[3];
    headAux[1] = lbias[0] + rb[0] + rb[1] + rb[2] + rb[3];
  }
}

// ---------------- stem weight pad+cast, PRE-SWIZZLED storage ----------------
__global__ __launch_bounds__(256) void fold_stem(const float* __restrict__ stw,
                                                 _Float16* __restrict__ Wst) {
  int idx = blockIdx.x * 256 + threadIdx.x;   // 1024*64
  int o = idx >> 6, j = idx & 63;
  int i = (((j >> 3) ^ (o & 7)) << 3) + (j & 7);
  Wst[idx] = (i < 26) ? (_Float16)stw[o * 26 + i] : (_Float16)0.f;
}

// ---------------- fused stem: LN(26) in-block + GEMM K=64 + bias/relu + stats ----------------
__global__ __launch_bounds__(256) void stem_gemm(
    const float* __restrict__ x, const float* __restrict__ stg, const float* __restrict__ stb,
    const _Float16* __restrict__ Wst, const float* __restrict__ stbias,
    _Float16* __restrict__ hout, float* __restrict__ stats_out, int rowBase) {
  __shared__ float xin[128 * 26];
  __shared__ _Float16 As[128 * 64];
  __shared__ _Float16 Bs[128 * 64];
  const int t = threadIdx.x;
  const int l = t & 63;
  const int w = t >> 6;
  const int wm = w >> 1, wn = w & 1;
  const int brow = blockIdx.x * 128;
  const int bcol = blockIdx.y * 128;

  // stage B (async, lands swizzled because Wst storage is pre-swizzled)
  const _Float16* gb = Wst + (size_t)(bcol + (t >> 3)) * 64 + (t & 7) * 8;
  char* lB = (char*)Bs + (size_t)w * 1024;
#pragma unroll
  for (int q = 0; q < 4; ++q) gload16(gb + (size_t)q * 32 * 64, lB + q * 4096);

  // raw x rows -> LDS (coalesced)
  const float* src = x + ((size_t)rowBase + brow) * 26;
  for (int i = t; i < 128 * 26; i += 256) xin[i] = src[i];
  __syncthreads();

  // LN per row (threads 0..127), write A-tile swizzled: chunk c stored at c^(row&7)
  if (t < 128) {
    float m = 0.f;
#pragma unroll
    for (int i = 0; i < 26; ++i) m += xin[t * 26 + i];
    m *= (1.f / 26.f);
    float v = 0.f;
#pragma unroll
    for (int i = 0; i < 26; ++i) { float d = xin[t * 26 + i] - m; v += d * d; }
    float rstd = rsqrtf(v * (1.f / 26.f) + EPSLN);
    _Float16 tmp[32];
#pragma unroll
    for (int i = 0; i < 26; ++i)
      tmp[i] = (_Float16)((xin[t * 26 + i] - m) * rstd * stg[i] + stb[i]);
#pragma unroll
    for (int i = 26; i < 32; ++i) tmp[i] = (_Float16)0.f;
    char* arow = (char*)As + t * 128;
#pragma unroll
    for (int c = 0; c < 4; ++c) {   // chunks 0..3 hold cols 0..31; 4..7 are zero
      f16x8 vv;
#pragma unroll
      for (int j = 0; j < 8; ++j) vv[j] = tmp[c * 8 + j];
      *(f16x8*)(arow + ((c ^ (t & 7)) << 4)) = vv;
    }
    f16x8 vz = (f16x8)(_Float16)0.f;
#pragma unroll
    for (int c = 4; c < 8; ++c) *(f16x8*)(arow + ((c ^ (t & 7)) << 4)) = vz;
  }
  __syncthreads();  // drains vmcnt (B staged) + lgkm (A written)

  f32x4 acc[4][4];
#pragma unroll
  for (int i = 0; i < 4; ++i)
#pragma unroll
    for (int j = 0; j < 4; ++j) acc[i][j] = (f32x4){0.f, 0.f, 0.f, 0.f};

#pragma unroll
  for (int ks = 0; ks < 2; ++ks) {
    const int cx = ((ks * 4 + (l >> 4)) ^ (l & 7)) << 4;
    f16x8 af[4], bfr[4];
#pragma unroll
    for (int m = 0; m < 4; ++m)
      af[m] = *(const f16x8*)((const char*)As + (wm * 64 + m * 16 + (l & 15)) * 128 + cx);
#pragma unroll
    for (int n = 0; n < 4; ++n)
      bfr[n] = *(const f16x8*)((const char*)Bs + (wn * 64 + n * 16 + (l & 15)) * 128 + cx);
#pragma unroll
    for (int m = 0; m < 4; ++m)
#pragma unroll
      for (int n = 0; n < 4; ++n)
        acc[m][n] = __builtin_amdgcn_mfma_f32_16x16x32_f16(af[m], bfr[n], acc[m][n], 0, 0, 0);
  }

  __syncthreads();               // done with xin; reuse as stats scratch
  float* sred = (float*)xin;     // 128 rows x {sum,sumsq}
  if (t < 256) sred[t] = 0.f;
  __syncthreads();

  float Bf[4];
#pragma unroll
  for (int n = 0; n < 4; ++n) Bf[n] = stbias[bcol + wn * 64 + n * 16 + (l & 15)];
#pragma unroll
  for (int m = 0; m < 4; ++m) {
#pragma unroll
    for (int rg = 0; rg < 4; ++rg) {
      int rloc = wm * 64 + m * 16 + (l >> 4) * 4 + rg;
      int lrow = brow + rloc;
      float ps = 0.f, psq = 0.f;
#pragma unroll
      for (int n = 0; n < 4; ++n) {
        int col = bcol + wn * 64 + n * 16 + (l & 15);
        float vv = fmaxf(acc[m][n][rg] + Bf[n], 0.f);
        hout[(size_t)lrow * HDIM + col] = (_Float16)vv;
        ps += vv; psq += vv * vv;
      }
#pragma unroll
      for (int off = 1; off < 16; off <<= 1) {
        ps += __shfl_xor(ps, off);
        psq += __shfl_xor(psq, off);
      }
      if ((l & 15) == 0) {
        atomicAdd(&sred[rloc * 2 + 0], ps);
        atomicAdd(&sred[rloc * 2 + 1], psq);
      }
    }
  }
  __syncthreads();
  if (t < 256) atomicAdd(&stats_out[(size_t)(brow + (t >> 1)) * 2 + (t & 1)], sred[t]);
}

// ---------------- per-layer fused GEMM, 256x256, BK=64, 4-phase/K-tile counted schedule ----------------
// 512 thr = 8 waves (2M x 4N); per-wave 128x64 = acc[8][4]. LDS: 2 bufs x (A 32KB | B 32KB).
// Phases per K-tile = C-quadrants (mh,nh): reads 12/4/8/0 ds_read_b128, 16 MFMA, trailing
// s_barrier. Stage(kt+2) into the SAME buffer, piece issued the phase after its region's last
// read: P1: A rows{0-63,128-191}; P2: B rows{0-127}; P3: B rows{128-255} + A rows{64-127,
// 192-255}. Boundary = vmcnt(8)+s_barrier (8 = stage(kt+2) in flight => stage(kt+1) landed).
// Swizzle: 128B rows, read chunk = nominal ^ (row&7); stage source pre-swizzled (rule #21).
__global__ __launch_bounds__(512, 2) void layer_gemm(
    const _Float16* __restrict__ hin, const float* __restrict__ stats_in,
    const _Float16* __restrict__ W, const float* __restrict__ bfold,
    const float* __restrict__ Sfold, _Float16* __restrict__ hout,
    float* __restrict__ stats_out) {
  __shared__ __align__(128) char smem[2 * 65536];  // buf p: A at p*65536, B at +32768
  const int t = threadIdx.x;
  const int l = t & 63;
  const int w = t >> 6;
  const int wm = w >> 2, wn = w & 3;
  int bid = blockIdx.x;
  {  // XCD chunk swizzle: contiguous bid range per XCD (A-panel groups share one L2)
    int nb = gridDim.x;
    if ((nb & 7) == 0) { int cpx = nb >> 3; bid = (bid & 7) * cpx + (bid >> 3); }
  }
  const int brow = (bid >> 2) * 256;   // consecutive bids share the A-panel
  const int bcol = (bid & 3) * 256;

  f32x4 acc[8][4];
#pragma unroll
  for (int i = 0; i < 8; ++i)
#pragma unroll
    for (int j = 0; j < 4; ++j) acc[i][j] = (f32x4){0.f, 0.f, 0.f, 0.f};

  // staging: one gload16 covers 64 rows (thread t -> row t>>3, chunk t&7, 128B rows).
  // source chunk pre-swizzled: cswz = (t&7) ^ (row&7) = (t&7) ^ ((t>>3)&7)
  const int cswz = (t & 7) ^ ((t >> 3) & 7);
  const _Float16* gA = hin + (size_t)(brow + (t >> 3)) * HDIM + cswz * 8;
  const _Float16* gB = W + (size_t)(bcol + (t >> 3)) * HDIM + cswz * 8;
  const int dstw = w << 10;  // wave-uniform LDS dest offset (lane adds l*16)

  auto stA0 = [&](int kt) {  // A rows {0-63, 128-191}
    char* d = smem + (kt & 1) * 65536 + dstw;
    const _Float16* s = gA + kt * 64;
    gload16(s, d);
    gload16(s + (size_t)128 * HDIM, d + 16384);
  };
  auto stA1 = [&](int kt) {  // A rows {64-127, 192-255}
    char* d = smem + (kt & 1) * 65536 + 8192 + dstw;
    const _Float16* s = gA + kt * 64;
    gload16(s + (size_t)64 * HDIM, d);
    gload16(s + (size_t)192 * HDIM, d + 16384);
  };
  auto stB0 = [&](int kt) {  // B rows {0-127}
    char* d = smem + (kt & 1) * 65536 + 32768 + dstw;
    const _Float16* s = gB + kt * 64;
    gload16(s, d);
    gload16(s + (size_t)64 * HDIM, d + 8192);
  };
  auto stB1 = [&](int kt) {  // B rows {128-255}
    char* d = smem + (kt & 1) * 65536 + 32768 + 16384 + dstw;
    const _Float16* s = gB + kt * 64;
    gload16(s + (size_t)128 * HDIM, d);
    gload16(s + (size_t)192 * HDIM, d + 8192);
  };

  const int rl = l & 15;
  const int abase = (wm * 128 + rl) * 128;          // + m*2048
  const int bbase = 32768 + (wn * 64 + rl) * 128;   // + n*2048
  const int cx0 = (((l >> 4) ^ (l & 7)) << 4);      // ks=0 chunk byte (row&7 == l&7)
  const int cx1 = (((4 | (l >> 4)) ^ (l & 7)) << 4);

#define PHASE_BAR()                     \
  do {                                  \
    __builtin_amdgcn_sched_barrier(0);  \
    __builtin_amdgcn_s_barrier();       \
    __builtin_amdgcn_sched_barrier(0);  \
  } while (0)
#define TILE_BOUND(N)                                      \
  do {                                                     \
    __builtin_amdgcn_sched_barrier(0);                     \
    asm volatile("s_waitcnt vmcnt(" #N ")" ::: "memory");  \
    __builtin_amdgcn_s_barrier();                          \
    __builtin_amdgcn_sched_barrier(0);                     \
  } while (0)

  auto tile = [&](int kt, bool st) {
    const char* bc = smem + (kt & 1) * 65536;
    f16x8 af[4][2], bf[4][2];
    // ---- P0 (mh0,nh0): read bf n0-1 + af m0-3; MFMA m0-3 x n0-1 ----
#pragma unroll
    for (int n = 0; n < 2; ++n) {
      bf[n][0] = *(const f16x8*)(bc + bbase + n * 2048 + cx0);
      bf[n][1] = *(const f16x8*)(bc + bbase + n * 2048 + cx1);
    }
#pragma unroll
    for (int m = 0; m < 4; ++m) {
      af[m][0] = *(const f16x8*)(bc + abase + m * 2048 + cx0);
      af[m][1] = *(const f16x8*)(bc + abase + m * 2048 + cx1);
    }
    __builtin_amdgcn_s_setprio(1);
#pragma unroll
    for (int m = 0; m < 4; ++m)
#pragma unroll
      for (int n = 0; n < 2; ++n) {
        acc[m][n] = __builtin_amdgcn_mfma_f32_16x16x32_f16(af[m][0], bf[n][0], acc[m][n], 0, 0, 0);
        acc[m][n] = __builtin_amdgcn_mfma_f32_16x16x32_f16(af[m][1], bf[n][1], acc[m][n], 0, 0, 0);
      }
    __builtin_amdgcn_s_setprio(0);
    PHASE_BAR();
    // ---- P1 (mh0,nh1): read bf n2-3; stage A-even(kt+2); MFMA m0-3 x n2-3 ----
#pragma unroll
    for (int n = 2; n < 4; ++n) {
      bf[n][0] = *(const f16x8*)(bc + bbase + n * 2048 + cx0);
      bf[n][1] = *(const f16x8*)(bc + bbase + n * 2048 + cx1);
    }
    if (st) stA0(kt + 2);
    __builtin_amdgcn_s_setprio(1);
#pragma unroll
    for (int m = 0; m < 4; ++m)
#pragma unroll
      for (int n = 2; n < 4; ++n) {
        acc[m][n] = __builtin_amdgcn_mfma_f32_16x16x32_f16(af[m][0], bf[n][0], acc[m][n], 0, 0, 0);
        acc[m][n] = __builtin_amdgcn_mfma_f32_16x16x32_f16(af[m][1], bf[n][1], acc[m][n], 0, 0, 0);
      }
    __builtin_amdgcn_s_setprio(0);
    PHASE_BAR();
    // ---- P2 (mh1,nh0): read af m4-7; stage B-lo(kt+2); MFMA m4-7 x n0-1 ----
#pragma unroll
    for (int j = 0; j < 4; ++j) {
      af[j][0] = *(const f16x8*)(bc + abase + (4 + j) * 2048 + cx0);
      af[j][1] = *(const f16x8*)(bc + abase + (4 + j) * 2048 + cx1);
    }
    if (st) stB0(kt + 2);
    __builtin_amdgcn_s_setprio(1);
#pragma unroll
    for (int j = 0; j < 4; ++j)
#pragma unroll
      for (int n = 0; n < 2; ++n) {
        acc[4 + j][n] = __builtin_amdgcn_mfma_f32_16x16x32_f16(af[j][0], bf[n][0], acc[4 + j][n], 0, 0, 0);
        acc[4 + j][n] = __builtin_amdgcn_mfma_f32_16x16x32_f16(af[j][1], bf[n][1], acc[4 + j][n], 0, 0, 0);
      }
    __builtin_amdgcn_s_setprio(0);
    PHASE_BAR();
    // ---- P3 (mh1,nh1): no reads; stage B-hi + A-odd (kt+2); MFMA m4-7 x n2-3 ----
    if (st) { stB1(kt + 2); stA1(kt + 2); }
    __builtin_amdgcn_s_setprio(1);
#pragma unroll
    for (int j = 0; j < 4; ++j)
#pragma unroll
      for (int n = 2; n < 4; ++n) {
        acc[4 + j][n] = __builtin_amdgcn_mfma_f32_16x16x32_f16(af[j][0], bf[n][0], acc[4 + j][n], 0, 0, 0);
        acc[4 + j][n] = __builtin_amdgcn_mfma_f32_16x16x32_f16(af[j][1], bf[n][1], acc[4 + j][n], 0, 0, 0);
      }
    __builtin_amdgcn_s_setprio(0);
    // boundary barrier added by caller (TILE_BOUND)
  };

  // prologue: stage K-tiles 0 and 1 fully
  stA0(0); stA1(0); stB0(0); stB1(0);
  stA0(1); stA1(1); stB0(1); stB1(1);
  TILE_BOUND(8);   // tile 0's 8 loads landed (8 = tile 1's still in flight)

#pragma unroll 1
  for (int kt = 0; kt < 14; ++kt) {
    tile(kt, true);
    TILE_BOUND(8); // 8 in flight = stage(kt+2); proves stage(kt+1) landed
  }
  tile(14, false);
  TILE_BOUND(0);   // drain stage(15)
  tile(15, false);
  __syncthreads(); // full drain before LDS reuse
#undef PHASE_BAR
#undef TILE_BOUND

  // ---- epilogue: LN-affine + relu + fp16 store; stats combined in LDS, then 1 atomic/row-val ----
  float* sred = (float*)smem;  // 256 rows x {sum, sumsq}
  sred[t] = 0.f;               // 512 threads cover 512 floats
  __syncthreads();

  float Sf[4], Bf2[4];
#pragma unroll
  for (int n = 0; n < 4; ++n) {
    int col = bcol + wn * 64 + n * 16 + (l & 15);
    Sf[n] = Sfold[col];
    Bf2[n] = bfold[col];
  }
#pragma unroll
  for (int m = 0; m < 8; ++m) {
#pragma unroll
    for (int rg = 0; rg < 4; ++rg) {
      int rloc = wm * 128 + m * 16 + (l >> 4) * 4 + rg;  // C/D: col=lane&15, row=(lane>>4)*4+reg
      int grow = brow + rloc;
      float sum = stats_in[(size_t)grow * 2 + 0];
      float sumsq = stats_in[(size_t)grow * 2 + 1];
      float mean = sum * (1.f / 1024.f);
      float rstd = rsqrtf(sumsq * (1.f / 1024.f) - mean * mean + EPSLN);
      float ps = 0.f, psq = 0.f;
#pragma unroll
      for (int n = 0; n < 4; ++n) {
        int col = bcol + wn * 64 + n * 16 + (l & 15);
        float vv = rstd * (acc[m][n][rg] - mean * Sf[n]) + Bf2[n];
        vv = fmaxf(vv, 0.f);
        hout[(size_t)grow * HDIM + col] = (_Float16)vv;
        ps += vv; psq += vv * vv;
      }
#pragma unroll
      for (int off2 = 1; off2 < 16; off2 <<= 1) {
        ps += __shfl_xor(ps, off2);
        psq += __shfl_xor(psq, off2);
      }
      if ((l & 15) == 0) {
        atomicAdd(&sred[rloc * 2 + 0], ps);
        atomicAdd(&sred[rloc * 2 + 1], psq);
      }
    }
  }
  __syncthreads();
  atomicAdd(&stats_out[(size_t)(brow + (t >> 1)) * 2 + (t & 1)], sred[t]);
}

// ---------------- head: out = sigmoid(rstd*(h8@W'' - mean*S'') + b''), one wave per row ----------------
__global__ __launch_bounds__(512) void head_kernel(
    const _Float16* __restrict__ h8, const float* __restrict__ stats8,
    const float* __restrict__ headW, const float* __restrict__ headAux,
    float* __restrict__ out, int rowBase) {
  int t = threadIdx.x, l = t & 63, w = t >> 6;
  int lrow = blockIdx.x * 8 + w;
  const f16x8* hp = (const f16x8*)(h8 + (size_t)lrow * HDIM) + l * 2;
  f16x8 v0 = hp[0], v1 = hp[1];
  float acc = 0.f;
#pragma unroll
  for (int j = 0; j < 8; ++j) acc += (float)v0[j] * headW[l * 16 + j];
#pragma unroll
  for (int j = 0; j < 8; ++j) acc += (float)v1[j] * headW[l * 16 + 8 + j];
#pragma unroll
  for (int off = 1; off < 64; off <<= 1) acc += __shfl_xor(acc, off);
  if (l == 0) {
    float sum = stats8[lrow * 2 + 0], sumsq = stats8[lrow * 2 + 1];
    float mean = sum * (1.f / 1024.f);
    float rstd = rsqrtf(sumsq * (1.f / 1024.f) - mean * mean + EPSLN);
    float z = rstd * (acc - mean * headAux[0]) + headAux[1];
    out[rowBase + lrow] = 1.f / (1.f + expf(-z));
  }
}

extern "C" void kernel_launch(void* const* d_in, const int* in_sizes, int n_in,
                              void* d_out, int out_size, void* d_ws, size_t ws_size,
                              hipStream_t stream) {
  const float* x      = (const float*)d_in[0];
  const float* stg    = (const float*)d_in[1];
  const float* stb    = (const float*)d_in[2];
  const float* stw    = (const float*)d_in[3];
  const float* stbias = (const float*)d_in[4];
  const float* bg     = (const float*)d_in[5];
  const float* bb     = (const float*)d_in[6];
  const float* bw     = (const float*)d_in[7];
  const float* bbias  = (const float*)d_in[8];
  const float* lg     = (const float*)d_in[9];
  const float* lb     = (const float*)d_in[10];
  const float* lw     = (const float*)d_in[11];
  const float* lbias  = (const float*)d_in[12];
  float* out = (float*)d_out;
  const int B = 65536;
  const int L = 8;

  char* ws = (char*)d_ws;
  size_t off = 0;
  auto carve = [&](size_t bytes) -> char* {
    char* p = ws + off;
    off = (off + bytes + 255) & ~(size_t)255;
    return p;
  };
  _Float16* Wf   = (_Float16*)carve((size_t)L * HDIM * HDIM * 2);
  float* bfold   = (float*)carve((size_t)L * HDIM * 4);
  float* Sfold   = (float*)carve((size_t)L * HDIM * 4);
  float* headW   = (float*)carve((size_t)HDIM * 4);
  float* headAux = (float*)carve(256);
  _Float16* Wst  = (_Float16*)carve((size_t)HDIM * 64 * 2);
  size_t fixed = off;

  // pick largest batch chunk R (power of 2, >=256) whose buffers fit in ws
  int R = B;
  while (R > 256) {
    size_t need = fixed + 2 * ((size_t)R * HDIM * 2 + 256) + ((size_t)9 * R * 2 * 4 + 256);
    if (need <= ws_size) break;
    R >>= 1;
  }
  _Float16* hA = (_Float16*)carve((size_t)R * HDIM * 2);
  _Float16* hB = (_Float16*)carve((size_t)R * HDIM * 2);
  float* stats = (float*)carve((size_t)9 * R * 2 * 4);  // 9 slots: h0..h8 (sum,sumsq)

  fold_blk<<<L * HDIM, 256, 0, stream>>>(bg, bb, bw, bbias, Wf, bfold, Sfold);
  fold_head<<<1, 256, 0, stream>>>(lg, lb, lw, lbias, headW, headAux);
  fold_stem<<<HDIM * 64 / 256, 256, 0, stream>>>(stw, Wst);

  const int nstats = 9 * R * 2;
  for (int c = 0; c < B / R; ++c) {
    int rowBase = c * R;
    zero_f32<<<(nstats + 255) / 256, 256, 0, stream>>>(stats, nstats);
    {
      dim3 grid(R / 128, 8);
      stem_gemm<<<grid, 256, 0, stream>>>(x, stg, stb, Wst, stbias, hA, stats, rowBase);
    }
    _Float16* cur = hA;
    _Float16* nxt = hB;
    for (int lyr = 0; lyr < L; ++lyr) {
      int nb = (R / 256) * 4;
      layer_gemm<<<nb, 512, 0, stream>>>(
          cur, stats + (size_t)lyr * R * 2, Wf + (size_t)lyr * HDIM * HDIM,
          bfold + lyr * HDIM, Sfold + lyr * HDIM, nxt, stats + (size_t)(lyr + 1) * R * 2);
      _Float16* tmp = cur; cur = nxt; nxt = tmp;
    }
    head_kernel<<<R / 8, 512, 0, stream>>>(cur, stats + (size_t)8 * R * 2, headW, headAux, out, rowBase);
  }
}